// Round 6
// baseline (71.247 us; speedup 1.0000x reference)
//
#include <hip/hip_runtime.h>
#include <math.h>

#define KC 3
#define S 12
#define SS 1728
#define AB 32
#define TLEN 64
#define NTHREADS 448
#define NWAVES 7
#define NSLICE 432
#define ROWW 13              // padded row width (gcd(13,32)=1 -> conflict-free strides)
#define LN2F 0.69314718055994530942f

__global__ __launch_bounds__(NTHREADS, 2)
void hmm_fwd_kernel(const int* __restrict__ ys,
                    const float* __restrict__ transition,  // [3][12][12]
                    const float* __restrict__ emission,    // [3][12][32]
                    const float* __restrict__ choice,      // [3]
                    const float* __restrict__ prior,       // [3][12]
                    float* __restrict__ out)
{
    // A-planes, each in its OWNER chain's row layout (144 rows x 13 pad):
    //   P0[13*(s1*12+s2) + s0], P1[13*(s0*12+s2) + s1], P2[13*(s0*12+s1) + s2]
    __shared__ float P0[144*ROWW], P1[144*ROWW], P2[144*ROWW];
    // beta in three orderings (same layouts as the matching plane):
    __shared__ float BR[144*ROWW], BQ[144*ROWW], BP[144*ROWW];
    __shared__ float ECt[KC*AB*S];   // [k][y][j], rows of 12
    __shared__ float T_s[KC][S][S];
    __shared__ float p_lin[KC][S];
    __shared__ float c_lin[KC];
    __shared__ int   ys_s[TLEN];
    __shared__ float wsum[NWAVES];

    const int tid = threadIdx.x;

    // ---------------- setup: linear-space tables ----------------
    if (tid < TLEN) ys_s[tid] = ys[tid];

    if (tid == 0) {
        float m = fmaxf(fmaxf(choice[0], choice[1]), choice[2]);
        float e0 = __expf(choice[0]-m), e1 = __expf(choice[1]-m), e2 = __expf(choice[2]-m);
        float inv = 1.f / (e0+e1+e2);
        c_lin[0] = e0*inv; c_lin[1] = e1*inv; c_lin[2] = e2*inv;
    }
    if (tid >= 1 && tid < 1 + KC) {
        int k = tid - 1;
        float m = -INFINITY;
        #pragma unroll
        for (int i = 0; i < S; ++i) m = fmaxf(m, prior[k*S + i]);
        float ev[S]; float s = 0.f;
        #pragma unroll
        for (int i = 0; i < S; ++i) { ev[i] = __expf(prior[k*S + i] - m); s += ev[i]; }
        float inv = 1.f / s;
        #pragma unroll
        for (int i = 0; i < S; ++i) p_lin[k][i] = ev[i] * inv;
    }
    if (tid >= 64 && tid < 64 + KC*S) {
        int r = tid - 64;
        int k = r / S, i = r % S;
        const float* row = transition + (k*S + i)*S;
        float m = -INFINITY;
        #pragma unroll
        for (int j = 0; j < S; ++j) m = fmaxf(m, row[j]);
        float ev[S]; float s = 0.f;
        #pragma unroll
        for (int j = 0; j < S; ++j) { ev[j] = __expf(row[j] - m); s += ev[j]; }
        float inv = 1.f / s;
        #pragma unroll
        for (int j = 0; j < S; ++j) T_s[k][i][j] = ev[j] * inv;
    }
    if (tid >= 128 && tid < 128 + KC*S) {    // emission -> ECt[k][y][j] = C[k]*softmax
        int r = tid - 128;
        int k = r / S, sj = r % S;
        float cm = fmaxf(fmaxf(choice[0], choice[1]), choice[2]);
        float ce = __expf(choice[k]-cm) /
                   (__expf(choice[0]-cm) + __expf(choice[1]-cm) + __expf(choice[2]-cm));
        const float* row = emission + (k*S + sj)*AB;
        float m = -INFINITY;
        #pragma unroll
        for (int a = 0; a < AB; ++a) m = fmaxf(m, row[a]);
        float ev[AB]; float s = 0.f;
        #pragma unroll
        for (int a = 0; a < AB; ++a) { ev[a] = __expf(row[a] - m); s += ev[a]; }
        float inv = ce / s;
        #pragma unroll
        for (int a = 0; a < AB; ++a) ECt[(k*AB + a)*S + sj] = ev[a] * inv;
    }
    __syncthreads();

    // ---------------- per-thread statics ----------------
    const bool active = tid < NSLICE;
    const int sk = tid / 144;          // chain
    const int q  = tid % 144;

    // phase-2 pointers (uniform code path for all chains)
    const float* rdp = (sk == 0) ? &BR[ROWW*q] : (sk == 1) ? &BQ[ROWW*q] : &BP[ROWW*q];
    float*       wrp = (sk == 0) ? &P0[ROWW*q] : (sk == 1) ? &P1[ROWW*q] : &P2[ROWW*q];
    const float* ecb = &ECt[sk*AB*S];

    // phase-1 statics: thread p handles natural states 4p..4p+3
    const int s0f = tid / 36;
    const int s1f = (4*tid % 144) / 12;
    const int s2b = (4*tid) % 12;
    const int bRo = ROWW*(12*s1f + s2b) + s0f;   // +13e
    const int bQo = ROWW*(12*s0f + s2b) + s1f;   // +13e
    const int bPo = ROWW*(12*s0f + s1f) + s2b;   // +e

    // T in registers, pinned via opaque v_mov (not rematerializable from LDS)
    float Treg[S][S];
    if (active) {
        #pragma unroll
        for (int i = 0; i < S; ++i) {
            #pragma unroll
            for (int j = 0; j < S; ++j) {
                float tmp = T_s[sk][i][j];
                asm volatile("v_mov_b32 %0, %1" : "=v"(Treg[i][j]) : "v"(tmp));
            }
        }
        // init plane_k[13q + j] = p_lin[sk][j] * pq * C[sk]
        float pq = (sk == 0) ? p_lin[1][q/12] * p_lin[2][q%12]
                 : (sk == 1) ? p_lin[0][q/12] * p_lin[2][q%12]
                 :             p_lin[0][q/12] * p_lin[1][q%12];
        float ck = c_lin[sk];
        #pragma unroll
        for (int j = 0; j < S; ++j) wrp[j] = p_lin[sk][j] * pq * ck;
    }
    __syncthreads();

    // ---------------- 64 steps, 2 barriers each ----------------
    float logR = 0.f, invR = 1.f;

    for (int t = 0; t < TLEN; ++t) {
        const int y = ys_s[t];

        if (active) {
            // phase 1: beta for 4 natural states; all strides conflict-free
            float b[4];
            #pragma unroll
            for (int e = 0; e < 4; ++e) {
                float r = P0[bRo + ROWW*e];
                float g = P1[bQo + ROWW*e];
                float h = P2[bPo + e];
                b[e] = (r + g + h) * invR;
            }
            #pragma unroll
            for (int e = 0; e < 4; ++e) {
                BR[bRo + ROWW*e] = b[e];
                BQ[bQo + ROWW*e] = b[e];
                BP[bPo + e]      = b[e];
            }
        }
        __syncthreads();   // barrier A: beta copies ready

        float o[S];
        if (active) {
            // ecol broadcast (issued first so latency hides under FMAs)
            const float* eb = &ecb[y*S];
            float4 e0 = *reinterpret_cast<const float4*>(&eb[0]);
            float4 e1 = *reinterpret_cast<const float4*>(&eb[4]);
            float4 e2 = *reinterpret_cast<const float4*>(&eb[8]);

            float bv[S];
            #pragma unroll
            for (int i = 0; i < S; ++i) bv[i] = rdp[i];   // contiguous, conflict-free

            float acc[S];
            #pragma unroll
            for (int j = 0; j < S; ++j) acc[j] = 0.f;
            #pragma unroll
            for (int i = 0; i < S; ++i) {
                const float bb = bv[i];
                #pragma unroll
                for (int j = 0; j < S; ++j) acc[j] = __builtin_fmaf(bb, Treg[i][j], acc[j]);
            }
            o[0] = acc[0]*e0.x; o[1] = acc[1]*e0.y; o[2]  = acc[2]*e0.z;  o[3]  = acc[3]*e0.w;
            o[4] = acc[4]*e1.x; o[5] = acc[5]*e1.y; o[6]  = acc[6]*e1.z;  o[7]  = acc[7]*e1.w;
            o[8] = acc[8]*e2.x; o[9] = acc[9]*e2.y; o[10] = acc[10]*e2.z; o[11] = acc[11]*e2.w;

            #pragma unroll
            for (int j = 0; j < S; ++j) wrp[j] = o[j];    // contiguous, conflict-free
        }

        if ((t & 7) == 7) {
            float part = 0.f;
            if (active) {
                #pragma unroll
                for (int j = 0; j < S; ++j) part += o[j];
            }
            #pragma unroll
            for (int w = 32; w > 0; w >>= 1) part += __shfl_xor(part, w);
            if ((tid & 63) == 0) wsum[tid >> 6] = part;
        }
        __syncthreads();   // barrier B: planes (and wsum on reduce steps) ready

        if ((t & 7) == 7 && t < TLEN-1) {
            float R = wsum[0];
            #pragma unroll
            for (int w = 1; w < NWAVES; ++w) R += wsum[w];
            invR = __builtin_amdgcn_rcpf(R);
            logR += __log2f(R);
        } else {
            invR = 1.f;
        }
    }

    // final: total mass at t=63 is in wsum (its normalizer never applied)
    if (tid == 0) {
        float R = wsum[0];
        #pragma unroll
        for (int w = 1; w < NWAVES; ++w) R += wsum[w];
        out[0] = LN2F * (__log2f(R) + logR);
    }
}

extern "C" void kernel_launch(void* const* d_in, const int* in_sizes, int n_in,
                              void* d_out, int out_size, void* d_ws, size_t ws_size,
                              hipStream_t stream) {
    const int*   ys         = (const int*)  d_in[0];
    const float* transition = (const float*)d_in[1];
    const float* emission   = (const float*)d_in[2];
    const float* choice     = (const float*)d_in[3];
    const float* prior      = (const float*)d_in[4];
    float* out = (float*)d_out;

    hipLaunchKernelGGL(hmm_fwd_kernel, dim3(1), dim3(NTHREADS), 0, stream,
                       ys, transition, emission, choice, prior, out);
}